// Round 6
// baseline (33.355 us; speedup 1.0000x reference)
//
#include <hip/hip_runtime.h>
#include <hip/hip_bf16.h>

#define NN    64
#define CC    256
#define PP    16
#define FMAP  4096   // CC*PP
#define KCH   128    // k-chunks of 32 rows for the W_g matvec split

// ---------------------------------------------------------------------------
// K1: 272 blocks x 256 threads.
//   blocks [0,256):  ub role — dual register-tiled GEMM producing U, Bm.
//   blocks [256,272): agg role — agg[m] = mean_n x[n][m] (hides under ub).
// ---------------------------------------------------------------------------
__global__ __launch_bounds__(256) void k1(const float* __restrict__ x,
                                          const float* __restrict__ We,
                                          const float* __restrict__ be,
                                          float* __restrict__ U,
                                          float* __restrict__ Bm,
                                          float* __restrict__ agg) {
    __shared__ float smem[6400];
    const int t = threadIdx.x;

    if (blockIdx.x >= 256) {
        // ================= agg role =================
        const int mb = blockIdx.x - 256;   // 0..15
        const int m  = mb * 256 + t;
        float s = 0.f;
        #pragma unroll
        for (int nn = 0; nn < 64; ++nn) s += x[(size_t)nn * FMAP + m];
        agg[m] = s * (1.0f / 64.0f);
        return;
    }

    // ================= ub role =================
    const int b    = blockIdx.x;
    const int o0   = (b & 7) * 32;
    const int col0 = (b >> 3) * 32;
    const int n0   = col0 >> 4;

    float* wts = smem;            // [kl][ol] : W1+W2, 64x32
    float* wt2 = smem + 2048;     // [kl][ol] : W2
    float* xs  = smem + 4096;     // [kl][cl] : X

    const int kq  = t >> 6;
    const int pos = t & 63;
    const int og  = pos >> 3;
    const int cg  = pos & 7;
    const int wol = t >> 3, wseg = t & 7;   // 32 o-rows x 8 segs of 8 k

    float acc1[4][4] = {{0.f}}, acc2[4][4] = {{0.f}};

    for (int ch = 0; ch < 4; ++ch) {
        const int kb = ch * 64;
        if (ch) __syncthreads();

        {
            const float* wr = We + (size_t)(o0 + wol) * 512 + kb + wseg * 8;
            float w1v[8], w2v[8];
            #pragma unroll
            for (int q = 0; q < 8; q += 4) {
                *(float4*)&w1v[q] = *(const float4*)(wr + q);
                *(float4*)&w2v[q] = *(const float4*)(wr + 256 + q);
            }
            #pragma unroll
            for (int q = 0; q < 8; ++q) {
                int kl = wseg * 8 + q;
                wts[kl * 32 + wol] = w1v[q] + w2v[q];
                wt2[kl * 32 + wol] = w2v[q];
            }
        }
        #pragma unroll
        for (int i = 0; i < 2; ++i) {
            int idx4 = t * 4 + i * 1024;
            int nl = idx4 >> 10, rem = idx4 & 1023;
            int kl = rem >> 4, p = rem & 15;
            float4 v = *(const float4*)&x[(size_t)(n0 + nl) * FMAP + (kb + kl) * PP + p];
            *(float4*)&xs[kl * 32 + nl * 16 + p] = v;
        }
        __syncthreads();

        const int kbase = kq * 16;
        #pragma unroll 8
        for (int kk = 0; kk < 16; ++kk) {
            int k = kbase + kk;
            const float4 a1 = *(const float4*)&wts[k * 32 + og * 4];
            const float4 a2 = *(const float4*)&wt2[k * 32 + og * 4];
            const float4 bx = *(const float4*)&xs [k * 32 + cg * 4];
            const float av1[4] = {a1.x, a1.y, a1.z, a1.w};
            const float av2[4] = {a2.x, a2.y, a2.z, a2.w};
            const float bv [4] = {bx.x, bx.y, bx.z, bx.w};
            #pragma unroll
            for (int i2 = 0; i2 < 4; ++i2)
                #pragma unroll
                for (int j = 0; j < 4; ++j) {
                    acc1[i2][j] = fmaf(av1[i2], bv[j], acc1[i2][j]);
                    acc2[i2][j] = fmaf(av2[i2], bv[j], acc2[i2][j]);
                }
        }
        __syncthreads();
    }

    // split-k reduction through LDS (stride-33 pad -> conflict-free)
    float* red = smem;   // needs 191*33+32 = 6335 <= 6400
    if (kq > 0) {
        float* dst = red + ((kq - 1) * 64 + pos) * 33;
        #pragma unroll
        for (int i2 = 0; i2 < 4; ++i2)
            #pragma unroll
            for (int j = 0; j < 4; ++j) {
                dst[i2 * 4 + j]      = acc1[i2][j];
                dst[16 + i2 * 4 + j] = acc2[i2][j];
            }
    }
    __syncthreads();
    if (kq == 0) {
        #pragma unroll
        for (int q = 0; q < 3; ++q) {
            const float* s = red + (q * 64 + pos) * 33;
            #pragma unroll
            for (int i2 = 0; i2 < 4; ++i2)
                #pragma unroll
                for (int j = 0; j < 4; ++j) {
                    acc1[i2][j] += s[i2 * 4 + j];
                    acc2[i2][j] += s[16 + i2 * 4 + j];
                }
        }
        const int nl = cg >> 2;
        const int p0 = (cg * 4) & 15;
        const int n  = n0 + nl;
        #pragma unroll
        for (int i2 = 0; i2 < 4; ++i2) {
            const int o = o0 + og * 4 + i2;
            const float bias = be[o];
            const float4 xv = *(const float4*)&x[(size_t)n * FMAP + o * PP + p0];
            float4 uo, bo;
            uo.x = xv.x - acc1[i2][0] - bias;
            uo.y = xv.y - acc1[i2][1] - bias;
            uo.z = xv.z - acc1[i2][2] - bias;
            uo.w = xv.w - acc1[i2][3] - bias;
            bo.x = acc2[i2][0]; bo.y = acc2[i2][1];
            bo.z = acc2[i2][2]; bo.w = acc2[i2][3];
            *(float4*)&U [(size_t)n * FMAP + o * PP + p0] = uo;
            *(float4*)&Bm[(size_t)n * FMAP + o * PP + p0] = bo;
        }
    }
}

// ---------------------------------------------------------------------------
// K2: 768 blocks x 256 threads.
//   blocks [0,256):  dist role — dispatched FIRST so it overlaps the stream.
//   blocks [256,768): mv role — pure W_g stream, fully unrolled 32 rows,
//                     agg in SGPRs, 4 independent accumulators.
// ---------------------------------------------------------------------------
__global__ __launch_bounds__(256) void k2(const float* __restrict__ U,
                                          const float* __restrict__ Bm,
                                          const float* __restrict__ Wg,
                                          const float* __restrict__ agg,
                                          float* __restrict__ part,
                                          float* __restrict__ edges) {
    const int t = threadIdx.x;

    if (blockIdx.x >= 256) {
        // ================= mv role =================
        const int mvb = blockIdx.x - 256;  // 0..511
        const int kc  = mvb >> 2;          // 32-row k chunk
        const int qx  = mvb & 3;           // m quarter
        const int m0  = qx * 1024 + t * 4;

        float ag[32];
        #pragma unroll
        for (int r4 = 0; r4 < 8; ++r4)
            *(float4*)&ag[r4 * 4] = *(const float4*)(agg + kc * 32 + r4 * 4);  // uniform -> s_load

        const float* wp = Wg + (size_t)kc * 32 * FMAP + m0;
        float4 ac0 = make_float4(0.f, 0.f, 0.f, 0.f);
        float4 ac1 = make_float4(0.f, 0.f, 0.f, 0.f);
        float4 ac2 = make_float4(0.f, 0.f, 0.f, 0.f);
        float4 ac3 = make_float4(0.f, 0.f, 0.f, 0.f);
        #pragma unroll
        for (int r = 0; r < 32; r += 4) {
            const float4 w0 = *(const float4*)(wp + (size_t)(r + 0) * FMAP);
            const float4 w1 = *(const float4*)(wp + (size_t)(r + 1) * FMAP);
            const float4 w2 = *(const float4*)(wp + (size_t)(r + 2) * FMAP);
            const float4 w3 = *(const float4*)(wp + (size_t)(r + 3) * FMAP);
            ac0.x = fmaf(ag[r], w0.x, ac0.x); ac0.y = fmaf(ag[r], w0.y, ac0.y);
            ac0.z = fmaf(ag[r], w0.z, ac0.z); ac0.w = fmaf(ag[r], w0.w, ac0.w);
            ac1.x = fmaf(ag[r+1], w1.x, ac1.x); ac1.y = fmaf(ag[r+1], w1.y, ac1.y);
            ac1.z = fmaf(ag[r+1], w1.z, ac1.z); ac1.w = fmaf(ag[r+1], w1.w, ac1.w);
            ac2.x = fmaf(ag[r+2], w2.x, ac2.x); ac2.y = fmaf(ag[r+2], w2.y, ac2.y);
            ac2.z = fmaf(ag[r+2], w2.z, ac2.z); ac2.w = fmaf(ag[r+2], w2.w, ac2.w);
            ac3.x = fmaf(ag[r+3], w3.x, ac3.x); ac3.y = fmaf(ag[r+3], w3.y, ac3.y);
            ac3.z = fmaf(ag[r+3], w3.z, ac3.z); ac3.w = fmaf(ag[r+3], w3.w, ac3.w);
        }
        float4 acc;
        acc.x = (ac0.x + ac1.x) + (ac2.x + ac3.x);
        acc.y = (ac0.y + ac1.y) + (ac2.y + ac3.y);
        acc.z = (ac0.z + ac1.z) + (ac2.z + ac3.z);
        acc.w = (ac0.w + ac1.w) + (ac2.w + ac3.w);
        *(float4*)&part[(size_t)kc * FMAP + m0] = acc;
        return;
    }

    // ================= dist role =================
    const int i0 = (blockIdx.x >> 4) * 4;
    const int j0 = (blockIdx.x & 15) * 4;

    float acc[4][4] = {{0.f}};
    #pragma unroll
    for (int s = 0; s < 4; ++s) {
        const int m = s * 1024 + t * 4;
        float4 u[4], b[4];
        #pragma unroll
        for (int jl = 0; jl < 4; ++jl) u[jl] = *(const float4*)&U [(size_t)(j0 + jl) * FMAP + m];
        #pragma unroll
        for (int il = 0; il < 4; ++il) b[il] = *(const float4*)&Bm[(size_t)(i0 + il) * FMAP + m];
        #pragma unroll
        for (int il = 0; il < 4; ++il)
            #pragma unroll
            for (int jl = 0; jl < 4; ++jl) {
                acc[il][jl] += fabsf(u[jl].x - b[il].x) + fabsf(u[jl].y - b[il].y)
                             + fabsf(u[jl].z - b[il].z) + fabsf(u[jl].w - b[il].w);
            }
    }
    #pragma unroll
    for (int il = 0; il < 4; ++il)
        #pragma unroll
        for (int jl = 0; jl < 4; ++jl) {
            float v = acc[il][jl];
            #pragma unroll
            for (int msk = 1; msk < 64; msk <<= 1) v += __shfl_xor(v, msk, 64);
            acc[il][jl] = v;
        }
    __shared__ float wred[4][16];
    const int w = t >> 6;
    if ((t & 63) == 0) {
        #pragma unroll
        for (int il = 0; il < 4; ++il)
            #pragma unroll
            for (int jl = 0; jl < 4; ++jl) wred[w][il * 4 + jl] = acc[il][jl];
    }
    __syncthreads();
    if (t < 16) {
        const int il = t >> 2, jl = t & 3;
        const int i = i0 + il, j = j0 + jl;
        float v = wred[0][t] + wred[1][t] + wred[2][t] + wred[3][t];
        edges[i * 64 + j] = (i == j) ? 1.0f : v;
    }
}

// ---------------------------------------------------------------------------
// K3: out role — 16 blocks x 256 threads, kb-parallel reduce + broadcast.
// ---------------------------------------------------------------------------
__global__ __launch_bounds__(256) void k3(const float* __restrict__ part,
                                          const float* __restrict__ bg,
                                          float* __restrict__ out) {
    const int t  = threadIdx.x;
    const int mb = blockIdx.x;            // 0..15
    const int kg = t >> 6;                // 4 kb-groups
    const int ml = t & 63;                // 64 float4 lanes
    const float* pp = part + (size_t)kg * 32 * FMAP + mb * 256 + ml * 4;
    float4 s = make_float4(0.f, 0.f, 0.f, 0.f);
    #pragma unroll
    for (int r = 0; r < 32; ++r) {
        const float4 v = *(const float4*)(pp + (size_t)r * FMAP);
        s.x += v.x; s.y += v.y; s.z += v.z; s.w += v.w;
    }
    __shared__ float4 red4[4][64];
    __shared__ float  rst[256];
    red4[kg][ml] = s;
    __syncthreads();
    if (t < 64) {
        const float4 a = red4[0][t], b = red4[1][t], c = red4[2][t], d = red4[3][t];
        const float4 bgv = *(const float4*)&bg[mb * 256 + t * 4];
        float4 r;
        r.x = a.x + b.x + c.x + d.x + bgv.x;
        r.y = a.y + b.y + c.y + d.y + bgv.y;
        r.z = a.z + b.z + c.z + d.z + bgv.z;
        r.w = a.w + b.w + c.w + d.w + bgv.w;
        *(float4*)&rst[t * 4] = r;
    }
    __syncthreads();
    const int row0 = t >> 6;    // 0..3
    const int c4   = t & 63;
    const float4 v = *(const float4*)&rst[c4 * 4];
    #pragma unroll
    for (int p = 0; p < 16; ++p) {
        const int n = p * 4 + row0;
        *(float4*)&out[(size_t)n * FMAP + mb * 256 + c4 * 4] = v;
    }
}

extern "C" void kernel_launch(void* const* d_in, const int* in_sizes, int n_in,
                              void* d_out, int out_size, void* d_ws, size_t ws_size,
                              hipStream_t stream) {
    const float* x  = (const float*)d_in[0];   // (64,1,256,4,4)
    const float* We = (const float*)d_in[1];   // (256,512)
    const float* be = (const float*)d_in[2];   // (256,)
    const float* Wg = (const float*)d_in[3];   // (4096,4096)
    const float* bg = (const float*)d_in[4];   // (4096,)
    float* out   = (float*)d_out;
    float* edges = out + (size_t)NN * FMAP;

    float* ws   = (float*)d_ws;
    float* U    = ws;                         // 262144 floats (1 MB)
    float* Bm   = U + (size_t)NN * FMAP;      // 262144 floats (1 MB)
    float* part = Bm + (size_t)NN * FMAP;     // KCH*FMAP = 524288 floats (2 MB)
    float* agg  = part + (size_t)KCH * FMAP;  // 4096 floats

    k1<<<dim3(272), 256, 0, stream>>>(x, We, be, U, Bm, agg);
    k2<<<dim3(768), 256, 0, stream>>>(U, Bm, Wg, agg, part, edges);
    k3<<<dim3(16),  256, 0, stream>>>(part, bg, out);
}

// Round 7
// 27.037 us; speedup vs baseline: 1.2337x; 1.2337x over previous
//
#include <hip/hip_runtime.h>
#include <hip/hip_bf16.h>

#define NN    64
#define CC    256
#define PP    16
#define FMAP  4096   // CC*PP
#define KCH   64     // k-chunks of 64 rows for the W_g matvec split

// ---------------------------------------------------------------------------
// K_big: 512 blocks x 256 threads.  (identical to R3 best-known)
//   blocks [0,256):  mv role  — inline agg for its 64-k chunk, then stream W_g
//                    into part[kb][m].  HBM-bound (64 MB).
//   blocks [256,512): ub role — dual register-tiled GEMM producing U, Bm.
// ---------------------------------------------------------------------------
__global__ __launch_bounds__(256) void k_big(const float* __restrict__ x,
                                             const float* __restrict__ We,
                                             const float* __restrict__ be,
                                             const float* __restrict__ Wg,
                                             float* __restrict__ U,
                                             float* __restrict__ Bm,
                                             float* __restrict__ part) {
    __shared__ float smem[3 * 4096];
    const int t = threadIdx.x;

    if (blockIdx.x < 256) {
        // ================= mv role =================
        const int qx = blockIdx.x & 3;    // m quarter
        const int kb = blockIdx.x >> 2;   // k chunk (64 k's)

        // inline agg[kb*64 + kl] = mean_n x[n][k]
        {
            const int kl = t & 63, q = t >> 6;
            float s = 0.f;
            #pragma unroll
            for (int nn = 0; nn < 16; ++nn)
                s += x[(size_t)(q * 16 + nn) * FMAP + kb * 64 + kl];
            smem[q * 64 + kl] = s;
        }
        __syncthreads();
        if (t < 64)
            smem[256 + t] = (smem[t] + smem[64 + t] + smem[128 + t] + smem[192 + t])
                            * (1.0f / 64.0f);
        __syncthreads();
        const float* aggs = smem + 256;

        const int m0 = qx * 1024 + t * 4;
        float4 acc = make_float4(0.f, 0.f, 0.f, 0.f);
        #pragma unroll 4
        for (int r4 = 0; r4 < 16; ++r4) {
            const float4 av = *(const float4*)&aggs[r4 * 4];
            const int k = kb * 64 + r4 * 4;
            const float4 w0 = *(const float4*)&Wg[(size_t)(k    ) * FMAP + m0];
            const float4 w1 = *(const float4*)&Wg[(size_t)(k + 1) * FMAP + m0];
            const float4 w2 = *(const float4*)&Wg[(size_t)(k + 2) * FMAP + m0];
            const float4 w3 = *(const float4*)&Wg[(size_t)(k + 3) * FMAP + m0];
            acc.x = fmaf(av.x, w0.x, acc.x); acc.y = fmaf(av.x, w0.y, acc.y);
            acc.z = fmaf(av.x, w0.z, acc.z); acc.w = fmaf(av.x, w0.w, acc.w);
            acc.x = fmaf(av.y, w1.x, acc.x); acc.y = fmaf(av.y, w1.y, acc.y);
            acc.z = fmaf(av.y, w1.z, acc.z); acc.w = fmaf(av.y, w1.w, acc.w);
            acc.x = fmaf(av.z, w2.x, acc.x); acc.y = fmaf(av.z, w2.y, acc.y);
            acc.z = fmaf(av.z, w2.z, acc.z); acc.w = fmaf(av.z, w2.w, acc.w);
            acc.x = fmaf(av.w, w3.x, acc.x); acc.y = fmaf(av.w, w3.y, acc.y);
            acc.z = fmaf(av.w, w3.z, acc.z); acc.w = fmaf(av.w, w3.w, acc.w);
        }
        *(float4*)&part[(size_t)kb * FMAP + m0] = acc;
        return;
    }

    // ================= ub role =================
    const int b    = blockIdx.x - 256;
    const int o0   = (b & 7) * 32;
    const int col0 = (b >> 3) * 32;
    const int n0   = col0 >> 4;

    float* wts = smem;            // [kl][ol] : W1+W2
    float* wt2 = smem + 4096;     // [kl][ol] : W2
    float* xs  = smem + 8192;     // [kl][cl] : X

    const int kq  = t >> 6;
    const int pos = t & 63;
    const int og  = pos >> 3;
    const int cg  = pos & 7;
    const int wol = t >> 3, wseg = t & 7;

    float acc1[4][4] = {{0.f}}, acc2[4][4] = {{0.f}};

    for (int ch = 0; ch < 2; ++ch) {
        const int kb = ch * 128;
        if (ch) __syncthreads();

        {
            const float* wr = We + (size_t)(o0 + wol) * 512 + kb + wseg * 16;
            float w1v[16], w2v[16];
            #pragma unroll
            for (int q = 0; q < 16; q += 4) {
                *(float4*)&w1v[q] = *(const float4*)(wr + q);
                *(float4*)&w2v[q] = *(const float4*)(wr + 256 + q);
            }
            #pragma unroll
            for (int q = 0; q < 16; ++q) {
                int kl = wseg * 16 + q;
                wts[kl * 32 + wol] = w1v[q] + w2v[q];
                wt2[kl * 32 + wol] = w2v[q];
            }
        }
        #pragma unroll
        for (int i = 0; i < 4; ++i) {
            int idx4 = t * 4 + i * 1024;
            int nl = idx4 >> 11, rem = idx4 & 2047;
            int kl = rem >> 4, p = rem & 15;
            float4 v = *(const float4*)&x[(size_t)(n0 + nl) * FMAP + (kb + kl) * PP + p];
            *(float4*)&xs[kl * 32 + nl * 16 + p] = v;
        }
        __syncthreads();

        const int kbase = kq * 32;
        #pragma unroll 8
        for (int kk = 0; kk < 32; ++kk) {
            int k = kbase + kk;
            const float4 a1 = *(const float4*)&wts[k * 32 + og * 4];
            const float4 a2 = *(const float4*)&wt2[k * 32 + og * 4];
            const float4 bx = *(const float4*)&xs [k * 32 + cg * 4];
            const float av1[4] = {a1.x, a1.y, a1.z, a1.w};
            const float av2[4] = {a2.x, a2.y, a2.z, a2.w};
            const float bv [4] = {bx.x, bx.y, bx.z, bx.w};
            #pragma unroll
            for (int i2 = 0; i2 < 4; ++i2)
                #pragma unroll
                for (int j = 0; j < 4; ++j) {
                    acc1[i2][j] = fmaf(av1[i2], bv[j], acc1[i2][j]);
                    acc2[i2][j] = fmaf(av2[i2], bv[j], acc2[i2][j]);
                }
        }
        __syncthreads();
    }

    float* red = smem;
    if (kq > 0) {
        float* dst = red + ((kq - 1) * 64 + pos) * 33;
        #pragma unroll
        for (int i2 = 0; i2 < 4; ++i2)
            #pragma unroll
            for (int j = 0; j < 4; ++j) {
                dst[i2 * 4 + j]      = acc1[i2][j];
                dst[16 + i2 * 4 + j] = acc2[i2][j];
            }
    }
    __syncthreads();
    if (kq == 0) {
        #pragma unroll
        for (int q = 0; q < 3; ++q) {
            const float* s = red + (q * 64 + pos) * 33;
            #pragma unroll
            for (int i2 = 0; i2 < 4; ++i2)
                #pragma unroll
                for (int j = 0; j < 4; ++j) {
                    acc1[i2][j] += s[i2 * 4 + j];
                    acc2[i2][j] += s[16 + i2 * 4 + j];
                }
        }
        const int nl = cg >> 2;
        const int p0 = (cg * 4) & 15;
        const int n  = n0 + nl;
        #pragma unroll
        for (int i2 = 0; i2 < 4; ++i2) {
            const int o = o0 + og * 4 + i2;
            const float bias = be[o];
            const float4 xv = *(const float4*)&x[(size_t)n * FMAP + o * PP + p0];
            float4 uo, bo;
            uo.x = xv.x - acc1[i2][0] - bias;
            uo.y = xv.y - acc1[i2][1] - bias;
            uo.z = xv.z - acc1[i2][2] - bias;
            uo.w = xv.w - acc1[i2][3] - bias;
            bo.x = acc2[i2][0]; bo.y = acc2[i2][1];
            bo.z = acc2[i2][2]; bo.w = acc2[i2][3];
            *(float4*)&U [(size_t)n * FMAP + o * PP + p0] = uo;
            *(float4*)&Bm[(size_t)n * FMAP + o * PP + p0] = bo;
        }
    }
}

// ---------------------------------------------------------------------------
// K_post: 272 blocks x 256 threads.
//   blocks [0,256):  dist role — 4x4 pair tiles, register abs-diff (as R3).
//   blocks [256,272): out role — kb-parallel reduce + broadcast (R5's fix).
// ---------------------------------------------------------------------------
__global__ __launch_bounds__(256) void k_post(const float* __restrict__ U,
                                              const float* __restrict__ Bm,
                                              const float* __restrict__ part,
                                              const float* __restrict__ bg,
                                              float* __restrict__ out,
                                              float* __restrict__ edges) {
    const int t = threadIdx.x;
    if (blockIdx.x < 256) {
        const int i0 = (blockIdx.x >> 4) * 4;
        const int j0 = (blockIdx.x & 15) * 4;

        float acc[4][4] = {{0.f}};
        #pragma unroll
        for (int s = 0; s < 4; ++s) {
            const int m = s * 1024 + t * 4;
            float4 u[4], b[4];
            #pragma unroll
            for (int jl = 0; jl < 4; ++jl) u[jl] = *(const float4*)&U [(size_t)(j0 + jl) * FMAP + m];
            #pragma unroll
            for (int il = 0; il < 4; ++il) b[il] = *(const float4*)&Bm[(size_t)(i0 + il) * FMAP + m];
            #pragma unroll
            for (int il = 0; il < 4; ++il)
                #pragma unroll
                for (int jl = 0; jl < 4; ++jl) {
                    acc[il][jl] += fabsf(u[jl].x - b[il].x) + fabsf(u[jl].y - b[il].y)
                                 + fabsf(u[jl].z - b[il].z) + fabsf(u[jl].w - b[il].w);
                }
        }
        #pragma unroll
        for (int il = 0; il < 4; ++il)
            #pragma unroll
            for (int jl = 0; jl < 4; ++jl) {
                float v = acc[il][jl];
                #pragma unroll
                for (int msk = 1; msk < 64; msk <<= 1) v += __shfl_xor(v, msk, 64);
                acc[il][jl] = v;
            }
        __shared__ float wred[4][16];
        const int w = t >> 6;
        if ((t & 63) == 0) {
            #pragma unroll
            for (int il = 0; il < 4; ++il)
                #pragma unroll
                for (int jl = 0; jl < 4; ++jl) wred[w][il * 4 + jl] = acc[il][jl];
        }
        __syncthreads();
        if (t < 16) {
            const int il = t >> 2, jl = t & 3;
            const int i = i0 + il, j = j0 + jl;
            float v = wred[0][t] + wred[1][t] + wred[2][t] + wred[3][t];
            edges[i * 64 + j] = (i == j) ? 1.0f : v;
        }
    } else {
        // out role: 16 blocks, one 256-m chunk each; kb-parallel reduction.
        const int mb = blockIdx.x - 256;      // 0..15
        const int kg = t >> 6;                // 4 kb-groups of 16 rows
        const int ml = t & 63;                // 64 float4 lanes
        const float* pp = part + (size_t)kg * 16 * FMAP + mb * 256 + ml * 4;
        float4 s = make_float4(0.f, 0.f, 0.f, 0.f);
        #pragma unroll
        for (int r = 0; r < 16; ++r) {
            const float4 v = *(const float4*)(pp + (size_t)r * FMAP);
            s.x += v.x; s.y += v.y; s.z += v.z; s.w += v.w;
        }
        __shared__ float4 red4[4][64];
        __shared__ float  rst[256];
        red4[kg][ml] = s;
        __syncthreads();
        if (t < 64) {
            const float4 a = red4[0][t], b = red4[1][t], c = red4[2][t], d = red4[3][t];
            const float4 bgv = *(const float4*)&bg[mb * 256 + t * 4];
            float4 r;
            r.x = a.x + b.x + c.x + d.x + bgv.x;
            r.y = a.y + b.y + c.y + d.y + bgv.y;
            r.z = a.z + b.z + c.z + d.z + bgv.z;
            r.w = a.w + b.w + c.w + d.w + bgv.w;
            *(float4*)&rst[t * 4] = r;
        }
        __syncthreads();
        const int row0 = t >> 6;    // 0..3
        const int c4   = t & 63;
        const float4 v = *(const float4*)&rst[c4 * 4];
        #pragma unroll
        for (int p = 0; p < 16; ++p) {
            const int n = p * 4 + row0;
            *(float4*)&out[(size_t)n * FMAP + mb * 256 + c4 * 4] = v;
        }
    }
}

extern "C" void kernel_launch(void* const* d_in, const int* in_sizes, int n_in,
                              void* d_out, int out_size, void* d_ws, size_t ws_size,
                              hipStream_t stream) {
    const float* x  = (const float*)d_in[0];   // (64,1,256,4,4)
    const float* We = (const float*)d_in[1];   // (256,512)
    const float* be = (const float*)d_in[2];   // (256,)
    const float* Wg = (const float*)d_in[3];   // (4096,4096)
    const float* bg = (const float*)d_in[4];   // (4096,)
    float* out   = (float*)d_out;
    float* edges = out + (size_t)NN * FMAP;

    float* ws   = (float*)d_ws;
    float* U    = ws;                        // 262144 floats (1 MB)
    float* Bm   = U + (size_t)NN * FMAP;     // 262144 floats (1 MB)
    float* part = Bm + (size_t)NN * FMAP;    // KCH*FMAP = 262144 floats (1 MB)

    k_big <<<dim3(512), 256, 0, stream>>>(x, We, be, Wg, U, Bm, part);
    k_post<<<dim3(272), 256, 0, stream>>>(U, Bm, part, bg, out, edges);
}